// Round 7
// baseline (171.911 us; speedup 1.0000x reference)
//
#include <hip/hip_runtime.h>

typedef unsigned short u16;
typedef unsigned int u32;
typedef unsigned long long u64;

typedef __bf16 bfrag __attribute__((ext_vector_type(8)));
typedef float f32x4 __attribute__((ext_vector_type(4)));

typedef __attribute__((address_space(1))) char* gas1_p;
typedef __attribute__((address_space(3))) char* las3_p;

#define DI __device__ __forceinline__

DI u16 f2bf(float f) {
  u32 u = __float_as_uint(f);
  u += 0x7FFFu + ((u >> 16) & 1u);
  return (u16)(u >> 16);
}
DI float bf2f(u16 h) { return __uint_as_float(((u32)h) << 16); }

DI void gload16(const void* g, void* l) {
  __builtin_amdgcn_global_load_lds((gas1_p)(u64)g, (las3_p)(u32)(u64)l, 16, 0, 0);
}

template <int N>
DI void waitvm() {
  if constexpr (N == 7)      asm volatile("s_waitcnt vmcnt(7)" ::: "memory");
  else if constexpr (N == 6) asm volatile("s_waitcnt vmcnt(6)" ::: "memory");
  else if constexpr (N == 4) asm volatile("s_waitcnt vmcnt(4)" ::: "memory");
  else                       asm volatile("s_waitcnt vmcnt(0)" ::: "memory");
}

// ------- 64x64 tile: straight split (hi/lo) and/or transposed (thi/tlo) ------
template <int WH, int WTH, int WTL>
__global__ __launch_bounds__(256) void k_trsplit64(const float* __restrict__ in,
                                                   u16* __restrict__ hi, u16* __restrict__ lo,
                                                   u16* __restrict__ thi, u16* __restrict__ tlo,
                                                   int rows, int cols) {
  __shared__ float tile[64][65];
  const u64 zoff = (u64)blockIdx.z * (u64)rows * (u64)cols;
  const int r0 = threadIdx.x >> 4;
  const int c4 = (threadIdx.x & 15) << 2;
  const float* src = in + zoff + (u64)(blockIdx.y * 64 + r0) * cols + blockIdx.x * 64 + c4;
#pragma unroll
  for (int p = 0; p < 4; ++p) {
    float4 v = *reinterpret_cast<const float4*>(src + (u64)(p * 16) * cols);
    tile[r0 + p * 16][c4 + 0] = v.x;
    tile[r0 + p * 16][c4 + 1] = v.y;
    tile[r0 + p * 16][c4 + 2] = v.z;
    tile[r0 + p * 16][c4 + 3] = v.w;
  }
  __syncthreads();
  if constexpr (WH) {
    const int rr = threadIdx.x >> 3;
    const int cc = (threadIdx.x & 7) << 3;
#pragma unroll
    for (int p = 0; p < 2; ++p) {
      const int r = rr + p * 32;
      u32 h[4], l[4];
#pragma unroll
      for (int j = 0; j < 4; ++j) {
        float a = tile[r][cc + 2 * j], b = tile[r][cc + 2 * j + 1];
        u16 ha = f2bf(a), hb = f2bf(b);
        h[j] = (u32)ha | ((u32)hb << 16);
        l[j] = (u32)f2bf(a - bf2f(ha)) | ((u32)f2bf(b - bf2f(hb)) << 16);
      }
      const u64 o = zoff + (u64)(blockIdx.y * 64 + r) * cols + blockIdx.x * 64 + cc;
      *reinterpret_cast<uint4*>(hi + o) = make_uint4(h[0], h[1], h[2], h[3]);
      *reinterpret_cast<uint4*>(lo + o) = make_uint4(l[0], l[1], l[2], l[3]);
    }
  }
  if constexpr (WTH) {
#pragma unroll
    for (int p = 0; p < 2; ++p) {
      const int id = threadIdx.x + p * 256;
      const int col = id >> 3;
      const int s8 = (id & 7) << 3;
      u32 h[4], l[4];
#pragma unroll
      for (int j = 0; j < 4; ++j) {
        float a = tile[s8 + 2 * j][col], b = tile[s8 + 2 * j + 1][col];
        u16 ha = f2bf(a), hb = f2bf(b);
        h[j] = (u32)ha | ((u32)hb << 16);
        if constexpr (WTL)
          l[j] = (u32)f2bf(a - bf2f(ha)) | ((u32)f2bf(b - bf2f(hb)) << 16);
      }
      const u64 o = zoff + (u64)(blockIdx.x * 64 + col) * rows + blockIdx.y * 64 + s8;
      *reinterpret_cast<uint4*>(thi + o) = make_uint4(h[0], h[1], h[2], h[3]);
      if constexpr (WTL)
        *reinterpret_cast<uint4*>(tlo + o) = make_uint4(l[0], l[1], l[2], l[3]);
    }
  }
}

// ===== unified 2-phase pipelined bt-GEMM (qproj + PV) ========================
template <int X3, int AF32, int BF32, int FM, int FN, int WR, int WC,
          int ADDMASK, int SPLITOUT>
__global__ __launch_bounds__(WR * WC * 64, 2) void k_gemmF(
    const void* Ap, const u16* Aploi, const void* Bp, const u16* Bploi,
    float* __restrict__ Cf, u16* __restrict__ Chi, u16* __restrict__ Clo,
    const float* __restrict__ Mask,
    int K, int N, int mt, int nt,
    u64 aStride, int aMask, u64 bStride, u64 cStride) {
  constexpr int NTHR = WR * WC * 64;
  constexpr int BM = WR * FM * 16, BN = WC * FN * 16;
  constexpr int ACH = AF32 ? ((BM * 9 + NTHR - 1) / NTHR) * NTHR : BM * 4;
  constexpr int BCH = BF32 ? ((BN * 9 + NTHR - 1) / NTHR) * NTHR : BN * 4;
  constexpr int A_SZ = AF32 ? ACH * 8 : BM * 32 * (1 + X3);
  constexpr int B_SZ = BF32 ? BCH * 8 : BN * 32 * (1 + X3);
  constexpr int AL0 = BM * 32;
  constexpr int BL0 = BN * 32;
  constexpr int TILE = A_SZ + B_SZ;
  constexpr int CA = ACH / NTHR, CB = BCH / NTHR;
  __shared__ u16 lds[2 * TILE];

  const int tid = threadIdx.x, lane = tid & 63;
  const int wid = tid >> 6, wr = wid / WC, wc = wid % WC;

  const int g = (blockIdx.x & 7) * (gridDim.x >> 3) + (blockIdx.x >> 3);
  const int z = g / (mt * nt);
  const int rem = g - z * (mt * nt);
  const int ty = rem / nt, tx = rem - ty * nt;

  const u64 aOff = (u64)(z & aMask) * aStride;
  const u64 bOff = (u64)z * bStride;
  const float* gAf = nullptr;
  const u16* gA = nullptr;
  const u16* gAl = nullptr;
  if constexpr (AF32) {
    gAf = (const float*)Ap + aOff + (u64)ty * (u32)BM * (u32)K;
  } else {
    gA = (const u16*)Ap + aOff + (u64)ty * (u32)BM * (u32)K;
    if constexpr (X3) gAl = Aploi + aOff + (u64)ty * (u32)BM * (u32)K;
  }
  const float* gBf = nullptr;
  const u16* gB = nullptr;
  const u16* gBl = nullptr;
  if constexpr (BF32) {
    gBf = (const float*)Bp + bOff + (u64)tx * (u32)BN * (u32)K;
  } else {
    gB = (const u16*)Bp + bOff + (u64)tx * (u32)BN * (u32)K;
    if constexpr (X3) gBl = Bploi + bOff + (u64)tx * (u32)BN * (u32)K;
  }

  u64 aG[CA]; u32 aLd[CA];
#pragma unroll
  for (int i = 0; i < CA; ++i) {
    const int c = i * NTHR + tid;
    if constexpr (AF32) {
      const int row = c / 9, cc = c - row * 9;
      aG[i] = (row < BM && cc < 8) ? ((u64)row * (u32)K + (u32)(cc * 4)) : 0;
      aLd[i] = c * 8;
    } else {
      const int row = c >> 2, ks = c & 3;
      aG[i] = (u64)row * (u32)K + (u32)((ks ^ ((row >> 1) & 3)) << 3);
      aLd[i] = c << 3;
    }
  }
  u64 bG[CB]; u32 bLd[CB];
#pragma unroll
  for (int i = 0; i < CB; ++i) {
    const int c = i * NTHR + tid;
    if constexpr (BF32) {
      const int row = c / 9, cc = c - row * 9;
      bG[i] = (row < BN && cc < 8) ? ((u64)row * (u32)K + (u32)(cc * 4)) : 0;
      bLd[i] = c * 8;
    } else {
      const int row = c >> 2, ks = c & 3;
      bG[i] = (u64)row * (u32)K + (u32)((ks ^ ((row >> 1) & 3)) << 3);
      bLd[i] = c << 3;
    }
  }

  f32x4 acc[FM][FN];
#pragma unroll
  for (int m = 0; m < FM; ++m)
#pragma unroll
    for (int n = 0; n < FN; ++n) acc[m][n] = (f32x4){0.f, 0.f, 0.f, 0.f};

  auto STAGE = [&](int bufU, int k0) {
#pragma unroll
    for (int i = 0; i < CA; ++i) {
      if constexpr (AF32) {
        gload16(gAf + aG[i] + (u32)k0, &lds[bufU + aLd[i]]);
      } else {
        gload16(gA + aG[i] + (u32)k0, &lds[bufU + aLd[i]]);
        if constexpr (X3) gload16(gAl + aG[i] + (u32)k0, &lds[bufU + AL0 + aLd[i]]);
      }
    }
#pragma unroll
    for (int i = 0; i < CB; ++i) {
      if constexpr (BF32) {
        gload16(gBf + bG[i] + (u32)k0, &lds[bufU + A_SZ + bLd[i]]);
      } else {
        gload16(gB + bG[i] + (u32)k0, &lds[bufU + A_SZ + bLd[i]]);
        if constexpr (X3) gload16(gBl + bG[i] + (u32)k0, &lds[bufU + A_SZ + BL0 + bLd[i]]);
      }
    }
  };

  const int swz = (((lane >> 1) & 3) ^ (lane >> 4)) << 3;
  auto COMPUTE = [&](int bufU) {
    bfrag ah[FM], al[FM], bh[FN], bl[FN];
#pragma unroll
    for (int m = 0; m < FM; ++m) {
      const int row = wr * (FM * 16) + m * 16 + (lane & 15);
      if constexpr (AF32) {
        const u32 base = bufU + (u32)row * 72 + (u32)(lane >> 4) * 16;
        f32x4 p0 = *reinterpret_cast<const f32x4*>(&lds[base]);
        f32x4 p1 = *reinterpret_cast<const f32x4*>(&lds[base + 8]);
#pragma unroll
        for (int j = 0; j < 8; ++j) {
          float f = j < 4 ? p0[j] : p1[j - 4];
          __bf16 h = (__bf16)f;
          ah[m][j] = h;
          al[m][j] = (__bf16)(f - (float)h);
        }
      } else {
        const int idx = bufU + row * 32 + swz;
        ah[m] = *reinterpret_cast<const bfrag*>(&lds[idx]);
        if constexpr (X3) al[m] = *reinterpret_cast<const bfrag*>(&lds[idx + AL0]);
      }
    }
#pragma unroll
    for (int n = 0; n < FN; ++n) {
      const int row = wc * (FN * 16) + n * 16 + (lane & 15);
      if constexpr (BF32) {
        const u32 base = bufU + A_SZ + (u32)row * 72 + (u32)(lane >> 4) * 16;
        f32x4 p0 = *reinterpret_cast<const f32x4*>(&lds[base]);
        f32x4 p1 = *reinterpret_cast<const f32x4*>(&lds[base + 8]);
#pragma unroll
        for (int j = 0; j < 8; ++j) {
          float f = j < 4 ? p0[j] : p1[j - 4];
          __bf16 h = (__bf16)f;
          bh[n][j] = h;
          bl[n][j] = (__bf16)(f - (float)h);
        }
      } else {
        const int idx = bufU + A_SZ + row * 32 + swz;
        bh[n] = *reinterpret_cast<const bfrag*>(&lds[idx]);
        if constexpr (X3) bl[n] = *reinterpret_cast<const bfrag*>(&lds[idx + BL0]);
      }
    }
#pragma unroll
    for (int m = 0; m < FM; ++m)
#pragma unroll
      for (int n = 0; n < FN; ++n) {
        acc[m][n] = __builtin_amdgcn_mfma_f32_16x16x32_bf16(ah[m], bh[n], acc[m][n], 0, 0, 0);
        if constexpr (X3) {
          acc[m][n] = __builtin_amdgcn_mfma_f32_16x16x32_bf16(ah[m], bl[n], acc[m][n], 0, 0, 0);
          acc[m][n] = __builtin_amdgcn_mfma_f32_16x16x32_bf16(al[m], bh[n], acc[m][n], 0, 0, 0);
        }
      }
  };

  const int NT = K >> 5;
  STAGE(0, 0);
  asm volatile("s_waitcnt vmcnt(0)" ::: "memory");
  __builtin_amdgcn_s_barrier();
  int buf = 0;
  for (int t = 0; t < NT; ++t) {
    if (t + 1 < NT) STAGE(TILE - buf, (t + 1) << 5);
    COMPUTE(buf);
    if (t + 1 < NT) {
      asm volatile("s_waitcnt vmcnt(0)" ::: "memory");
      __builtin_amdgcn_s_barrier();
      buf = TILE - buf;
    }
  }

  const u64 cOff = (u64)z * cStride;
  const u64 mOff = (u64)(z & aMask) * cStride;
  const int rB = ty * BM + wr * (FM * 16) + (lane >> 4) * 4;
  const int cB = tx * BN + wc * (FN * 16) + (lane & 15);
#pragma unroll
  for (int m = 0; m < FM; ++m)
#pragma unroll
    for (int n = 0; n < FN; ++n)
#pragma unroll
      for (int j = 0; j < 4; ++j) {
        const int rr = rB + m * 16 + j, cc = cB + n * 16;
        const u64 ci = cOff + (u64)rr * (u32)N + (u32)cc;
        float v = acc[m][n][j];
        if constexpr (ADDMASK) v += Mask[mOff + (u64)rr * (u32)N + (u32)cc];
        if constexpr (SPLITOUT) {
          u16 h = f2bf(v);
          Chi[ci] = h;
          Clo[ci] = f2bf(v - bf2f(h));
        } else {
          Cf[ci] = v;
        }
      }
}

// ===== scores: 4-phase-per-K-tile, 3-buf, counted-vmcnt(7), setprio ==========
// C[z][t][s] = sum_r qp[b][t][r]*kvs[z][s][r] + mask.  BM=256 BN=128 BK=32.
// 8 waves (4Mx2N), 64x64 wave tiles.  Per K-tile: 4 quadrant phases, each
// {4-8 ds_reads || 1-2 stage issues of tile t+2; s_barrier; setprio(1);
//  12 MFMA; setprio(0); s_barrier}.  vmcnt(7) once per K-tile (tile t+2's
//  loads stay in flight across the whole next iteration).
__global__ __launch_bounds__(512, 2) void k_s8(
    const u16* __restrict__ Ah, const u16* __restrict__ Al,
    const float* __restrict__ Bf, const float* __restrict__ Mask,
    float* __restrict__ Cf) {
  constexpr int ALO = 8192, B0 = 16384, TILE = 25600;  // u16 units per buf
  __shared__ u16 lds[3 * TILE];                        // 150 KB
  const int tid = threadIdx.x, lane = tid & 63;
  const int wid = tid >> 6, wr = wid >> 1, wc = wid & 1;

  const int g = (blockIdx.x & 7) * 32 + (blockIdx.x >> 3);  // XCD-chunked
  const int z = g >> 3;
  const int rem = g & 7;
  const int ty = rem >> 2, tx = rem & 3;
  const int b = z & 7;

  const u16* gAh = Ah + (u64)b * 524288 + (u64)ty * 256 * 1024;
  const u16* gAl = Al + (u64)b * 524288 + (u64)ty * 256 * 1024;
  const float* gB = Bf + (u64)z * 524288 + (u64)tx * 128 * 1024;

  // 7 staging chunks/thread/K-tile: i=0,1 A-hi, 2,3 A-lo, 4,5,6 B (i=6 dup-tail)
  u32 gOf[7]; u32 dOf[7];
#pragma unroll
  for (int i = 0; i < 7; ++i) {
    const int c = (i < 6) ? i * 512 + tid : 3072 + (tid & 127);
    if (c < 2048) {
      const int c2 = c & 1023, row = c2 >> 2, ks = c2 & 3;
      gOf[i] = (u32)row * 1024u + (u32)((ks ^ ((row >> 1) & 3)) << 3);
      dOf[i] = (u32)((c < 1024 ? 0 : ALO) + c2 * 8);
    } else {
      const int cb = c - 2048, row = cb / 9, cc = cb - row * 9;
      gOf[i] = (cc < 8) ? ((u32)row * 1024u + (u32)(cc * 4)) : 0u;
      dOf[i] = (u32)(B0 + cb * 8);
    }
  }

  f32x4 acc[4][4];
#pragma unroll
  for (int m = 0; m < 4; ++m)
#pragma unroll
    for (int n = 0; n < 4; ++n) acc[m][n] = (f32x4){0.f, 0.f, 0.f, 0.f};

  const int swz = (((lane >> 1) & 3) ^ (lane >> 4)) << 3;
  bfrag ah[2], al[2], bh[2], bl[2];

  auto rdA = [&](int rb, int fm, int d) {
    const int idx = rb + (wr * 64 + fm * 16 + (lane & 15)) * 32 + swz;
    ah[d] = *reinterpret_cast<const bfrag*>(&lds[idx]);
    al[d] = *reinterpret_cast<const bfrag*>(&lds[idx + ALO]);
  };
  auto rdB = [&](int rb, int fn, int d) {
    const u32 base = (u32)rb + B0 + (u32)(wc * 64 + fn * 16 + (lane & 15)) * 72 +
                     (u32)(lane >> 4) * 16;
    f32x4 p0 = *reinterpret_cast<const f32x4*>(&lds[base]);
    f32x4 p1 = *reinterpret_cast<const f32x4*>(&lds[base + 8]);
#pragma unroll
    for (int j = 0; j < 8; ++j) {
      float f = j < 4 ? p0[j] : p1[j - 4];
      __bf16 h = (__bf16)f;
      bh[d][j] = h;
      bl[d][j] = (__bf16)(f - (float)h);
    }
  };
  auto MFMA12 = [&](int mp, int np) {
#pragma unroll
    for (int di = 0; di < 2; ++di)
#pragma unroll
      for (int dj = 0; dj < 2; ++dj) {
        f32x4 a = acc[mp * 2 + di][np * 2 + dj];
        a = __builtin_amdgcn_mfma_f32_16x16x32_bf16(ah[di], bh[dj], a, 0, 0, 0);
        a = __builtin_amdgcn_mfma_f32_16x16x32_bf16(ah[di], bl[dj], a, 0, 0, 0);
        a = __builtin_amdgcn_mfma_f32_16x16x32_bf16(al[di], bh[dj], a, 0, 0, 0);
        acc[mp * 2 + di][np * 2 + dj] = a;
      }
  };

#define STG(i, SRC, SB, K2) gload16(SRC + gOf[i] + (u32)(K2), &lds[(SB) + dOf[i]])

  // prologue: stage tiles 0 and 1 fully
#pragma unroll
  for (int tt = 0; tt < 2; ++tt) {
    const int sb = tt * TILE, k2 = tt * 32;
    STG(0, gAh, sb, k2); STG(1, gAh, sb, k2);
    STG(2, gAl, sb, k2); STG(3, gAl, sb, k2);
    STG(4, gB, sb, k2);  STG(5, gB, sb, k2);  STG(6, gB, sb, k2);
  }
  waitvm<7>();
  __builtin_amdgcn_s_barrier();

  int bufIdx = 0;
  for (int t = 0; t < 32; ++t) {
    const int rb = bufIdx * TILE;
    int sbIdx = bufIdx + 2; if (sbIdx >= 3) sbIdx -= 3;
    const int sb = sbIdx * TILE;
    const int k2 = (t + 2) << 5;
    const bool st = (t + 2) < 32;

    // phase 0: quadrant (0,0) — read a01, b01
    rdA(rb, 0, 0); rdA(rb, 1, 1);
    rdB(rb, 0, 0); rdB(rb, 1, 1);
    if (st) { STG(0, gAh, sb, k2); STG(1, gAh, sb, k2); }
    __builtin_amdgcn_s_barrier();
    __builtin_amdgcn_s_setprio(1);
    MFMA12(0, 0);
    __builtin_amdgcn_s_setprio(0);
    __builtin_amdgcn_s_barrier();

    // phase 1: quadrant (0,1) — new b23, reuse a01
    rdB(rb, 2, 0); rdB(rb, 3, 1);
    if (st) { STG(2, gAl, sb, k2); STG(3, gAl, sb, k2); }
    __builtin_amdgcn_s_barrier();
    __builtin_amdgcn_s_setprio(1);
    MFMA12(0, 1);
    __builtin_amdgcn_s_setprio(0);
    __builtin_amdgcn_s_barrier();

    // phase 2: quadrant (1,1) — new a23, reuse b23
    rdA(rb, 2, 0); rdA(rb, 3, 1);
    if (st) { STG(4, gB, sb, k2); STG(5, gB, sb, k2); }
    __builtin_amdgcn_s_barrier();
    __builtin_amdgcn_s_setprio(1);
    MFMA12(1, 1);
    __builtin_amdgcn_s_setprio(0);
    __builtin_amdgcn_s_barrier();

    // phase 3: quadrant (1,0) — re-read b01, reuse a23
    rdB(rb, 0, 0); rdB(rb, 1, 1);
    if (st) { STG(6, gB, sb, k2); }
    __builtin_amdgcn_s_barrier();
    __builtin_amdgcn_s_setprio(1);
    MFMA12(1, 0);
    __builtin_amdgcn_s_setprio(0);
    if (st) waitvm<7>(); else waitvm<0>();
    __builtin_amdgcn_s_barrier();

    bufIdx = bufIdx + 1; if (bufIdx >= 3) bufIdx -= 3;
  }
#undef STG

  // epilogue: +mask, write f32 scores
  const u64 cOff = (u64)z * 262144;
  const int rB = ty * 256 + wr * 64 + (lane >> 4) * 4;
  const int cB = tx * 128 + wc * 64 + (lane & 15);
#pragma unroll
  for (int m = 0; m < 4; ++m)
#pragma unroll
    for (int n = 0; n < 4; ++n)
#pragma unroll
      for (int j = 0; j < 4; ++j) {
        const int rr = rB + m * 16 + j, cc = cB + n * 16;
        float v = acc[m][n][j] + Mask[((u64)(b * 512 + rr)) * 512 + (u32)cc];
        Cf[cOff + (u64)rr * 512 + (u32)cc] = v;
      }
}

// --------- softmax over s (one wave per row), fp32 in (mask pre-added) -------
__global__ __launch_bounds__(256) void k_softmax(const float* __restrict__ sc,
                                                 u16* __restrict__ attn) {
  const int row = blockIdx.x * 4 + (threadIdx.x >> 6);
  const int lane = threadIdx.x & 63;
  const float* srow = sc + (u64)row * 512 + lane * 8;
  float4 s0 = *reinterpret_cast<const float4*>(srow);
  float4 s1 = *reinterpret_cast<const float4*>(srow + 4);
  float x[8] = {s0.x, s0.y, s0.z, s0.w, s1.x, s1.y, s1.z, s1.w};
  float mx = x[0];
#pragma unroll
  for (int j = 1; j < 8; ++j) mx = fmaxf(mx, x[j]);
#pragma unroll
  for (int off = 32; off > 0; off >>= 1) mx = fmaxf(mx, __shfl_xor(mx, off));
  float sum = 0.f;
#pragma unroll
  for (int j = 0; j < 8; ++j) {
    x[j] = __expf(x[j] - mx);
    sum += x[j];
  }
#pragma unroll
  for (int off = 32; off > 0; off >>= 1) sum += __shfl_xor(sum, off);
  const float inv = 1.f / sum;
  u32 o[4];
#pragma unroll
  for (int j = 0; j < 4; ++j) {
    u16 e0 = f2bf(x[2 * j] * inv), e1 = f2bf(x[2 * j + 1] * inv);
    o[j] = (u32)e0 | ((u32)e1 << 16);
  }
  *reinterpret_cast<uint4*>(attn + (u64)row * 512 + lane * 8) = make_uint4(o[0], o[1], o[2], o[3]);
}

// -----------------------------------------------------------------------------
extern "C" void kernel_launch(void* const* d_in, const int* in_sizes, int n_in,
                              void* d_out, int out_size, void* d_ws, size_t ws_size,
                              hipStream_t stream) {
  // N=4, B=8, T=512, S=512, E=1024, R=1024
  const float* q = (const float*)d_in[0];
  const float* kvs = (const float*)d_in[1];
  const float* mask = (const float*)d_in[2];
  const float* Wk = (const float*)d_in[3];  // bk unused (constant over s)
  float* out = (float*)d_out;

  char* w = (char*)d_ws;
  u16* attn = (u16*)(w + 0);
  u16* wkt_hi = (u16*)(w + 16777216);
  u16* wkt_lo = (u16*)(w + 18874368);
  u16* qp_hi = (u16*)(w + 20971520);
  u16* qp_lo = (u16*)(w + 29360128);
  u16* kvt_hi = (u16*)(w + 104857600);
  float* sc = (float*)(w + 138412032);

  // 1) Wk [e][r] -> transposed split wkt[r][e] hi/lo
  k_trsplit64<0, 1, 1><<<dim3(16, 16, 1), dim3(256), 0, stream>>>(
      Wk, (u16*)nullptr, (u16*)nullptr, wkt_hi, wkt_lo, 1024, 1024);
  // 2) kvs -> transposed hi: kvt[z][r][s]
  k_trsplit64<0, 1, 0><<<dim3(16, 8, 32), dim3(256), 0, stream>>>(
      kvs, (u16*)nullptr, (u16*)nullptr, kvt_hi, (u16*)nullptr, 512, 1024);
  // 3) qproj[bt][r] = q[bt][e]*wkt[r][e]; A raw f32 (in-reg split), x3, split-out
  k_gemmF<1, 1, 0, 4, 4, 2, 2, 0, 1><<<dim3(256), dim3(256), 0, stream>>>(
      q, (const u16*)nullptr, wkt_hi, wkt_lo,
      (float*)nullptr, qp_hi, qp_lo, (const float*)nullptr,
      1024, 1024, 32, 8, (u64)0, 0, (u64)0, (u64)0);
  // 4) scores: 4-phase 3-buf counted-vmcnt kernel; 256 blocks, 512 thr
  k_s8<<<dim3(256), dim3(512), 0, stream>>>(qp_hi, qp_lo, kvs, mask, sc);
  // 5) softmax(sc) -> attn bf16
  k_softmax<<<dim3(4096), dim3(256), 0, stream>>>(sc, attn);
  // 6) out[z][t][r] = attn[z][t][s]*kvt[z][r][s]; bf16 x1; 256x128, 512 blocks
  k_gemmF<0, 0, 0, 8, 4, 2, 2, 0, 0><<<dim3(512), dim3(256), 0, stream>>>(
      attn, (const u16*)nullptr, kvt_hi, (const u16*)nullptr,
      out, (u16*)nullptr, (u16*)nullptr, (const float*)nullptr,
      512, 1024, 2, 8, (u64)262144, 31, (u64)524288, (u64)524288);

  (void)in_sizes; (void)n_in; (void)out_size; (void)ws_size;
}

// Round 8
// 161.838 us; speedup vs baseline: 1.0622x; 1.0622x over previous
//
#include <hip/hip_runtime.h>

typedef unsigned short u16;
typedef unsigned int u32;
typedef unsigned long long u64;

typedef __bf16 bfrag __attribute__((ext_vector_type(8)));
typedef float f32x4 __attribute__((ext_vector_type(4)));

typedef __attribute__((address_space(1))) char* gas1_p;
typedef __attribute__((address_space(3))) char* las3_p;

#define DI __device__ __forceinline__

DI u16 f2bf(float f) {
  u32 u = __float_as_uint(f);
  u += 0x7FFFu + ((u >> 16) & 1u);
  return (u16)(u >> 16);
}
DI float bf2f(u16 h) { return __uint_as_float(((u32)h) << 16); }

DI void gload16(const void* g, void* l) {
  __builtin_amdgcn_global_load_lds((gas1_p)(u64)g, (las3_p)(u32)(u64)l, 16, 0, 0);
}

// ------- 64x64 tile: straight split (hi/lo) and/or transposed (thi/tlo) ------
template <int WH, int WTH, int WTL>
__global__ __launch_bounds__(256) void k_trsplit64(const float* __restrict__ in,
                                                   u16* __restrict__ hi, u16* __restrict__ lo,
                                                   u16* __restrict__ thi, u16* __restrict__ tlo,
                                                   int rows, int cols) {
  __shared__ float tile[64][65];
  const u64 zoff = (u64)blockIdx.z * (u64)rows * (u64)cols;
  const int r0 = threadIdx.x >> 4;
  const int c4 = (threadIdx.x & 15) << 2;
  const float* src = in + zoff + (u64)(blockIdx.y * 64 + r0) * cols + blockIdx.x * 64 + c4;
#pragma unroll
  for (int p = 0; p < 4; ++p) {
    float4 v = *reinterpret_cast<const float4*>(src + (u64)(p * 16) * cols);
    tile[r0 + p * 16][c4 + 0] = v.x;
    tile[r0 + p * 16][c4 + 1] = v.y;
    tile[r0 + p * 16][c4 + 2] = v.z;
    tile[r0 + p * 16][c4 + 3] = v.w;
  }
  __syncthreads();
  if constexpr (WH) {
    const int rr = threadIdx.x >> 3;
    const int cc = (threadIdx.x & 7) << 3;
#pragma unroll
    for (int p = 0; p < 2; ++p) {
      const int r = rr + p * 32;
      u32 h[4], l[4];
#pragma unroll
      for (int j = 0; j < 4; ++j) {
        float a = tile[r][cc + 2 * j], b = tile[r][cc + 2 * j + 1];
        u16 ha = f2bf(a), hb = f2bf(b);
        h[j] = (u32)ha | ((u32)hb << 16);
        l[j] = (u32)f2bf(a - bf2f(ha)) | ((u32)f2bf(b - bf2f(hb)) << 16);
      }
      const u64 o = zoff + (u64)(blockIdx.y * 64 + r) * cols + blockIdx.x * 64 + cc;
      *reinterpret_cast<uint4*>(hi + o) = make_uint4(h[0], h[1], h[2], h[3]);
      *reinterpret_cast<uint4*>(lo + o) = make_uint4(l[0], l[1], l[2], l[3]);
    }
  }
  if constexpr (WTH) {
#pragma unroll
    for (int p = 0; p < 2; ++p) {
      const int id = threadIdx.x + p * 256;
      const int col = id >> 3;
      const int s8 = (id & 7) << 3;
      u32 h[4], l[4];
#pragma unroll
      for (int j = 0; j < 4; ++j) {
        float a = tile[s8 + 2 * j][col], b = tile[s8 + 2 * j + 1][col];
        u16 ha = f2bf(a), hb = f2bf(b);
        h[j] = (u32)ha | ((u32)hb << 16);
        if constexpr (WTL)
          l[j] = (u32)f2bf(a - bf2f(ha)) | ((u32)f2bf(b - bf2f(hb)) << 16);
      }
      const u64 o = zoff + (u64)(blockIdx.x * 64 + col) * rows + blockIdx.y * 64 + s8;
      *reinterpret_cast<uint4*>(thi + o) = make_uint4(h[0], h[1], h[2], h[3]);
      if constexpr (WTL)
        *reinterpret_cast<uint4*>(tlo + o) = make_uint4(l[0], l[1], l[2], l[3]);
    }
  }
}

// ===== unified 2-phase pipelined bt-GEMM ====================================
// C[z][m][n] = sum_k A[z][m][k]*B[z][n][k].
// AF32/BF32: operand staged raw f32 (144B padded rows), in-register hi/lo split.
// WRKVT (requires BF32): the 4 ty-duplicate blocks each transpose-write a
//   disjoint 8-row r-slice of the staged f32 B-tile as bf16 -> KvtOut[z][r][s]
//   (folds the kvt transpose kernel into scores; LDS reads bank-rotated,
//   stores issued before COMPUTE so MFMA hides the ack).
template <int X3, int AF32, int BF32, int FM, int FN, int WR, int WC,
          int ADDMASK, int SPLITOUT, int WRKVT>
__global__ __launch_bounds__(WR * WC * 64, 2) void k_gemmF(
    const void* Ap, const u16* Aploi, const void* Bp, const u16* Bploi,
    float* __restrict__ Cf, u16* __restrict__ Chi, u16* __restrict__ Clo,
    const float* __restrict__ Mask, u16* __restrict__ KvtOut,
    int K, int N, int mt, int nt,
    u64 aStride, int aMask, u64 bStride, u64 cStride) {
  constexpr int NTHR = WR * WC * 64;
  constexpr int BM = WR * FM * 16, BN = WC * FN * 16;
  constexpr int ACH = AF32 ? ((BM * 9 + NTHR - 1) / NTHR) * NTHR : BM * 4;
  constexpr int BCH = BF32 ? ((BN * 9 + NTHR - 1) / NTHR) * NTHR : BN * 4;
  constexpr int A_SZ = AF32 ? ACH * 8 : BM * 32 * (1 + X3);
  constexpr int B_SZ = BF32 ? BCH * 8 : BN * 32 * (1 + X3);
  constexpr int AL0 = BM * 32;
  constexpr int BL0 = BN * 32;
  constexpr int TILE = A_SZ + B_SZ;
  constexpr int CA = ACH / NTHR, CB = BCH / NTHR;
  __shared__ u16 lds[2 * TILE];

  const int tid = threadIdx.x, lane = tid & 63;
  const int wid = tid >> 6, wr = wid / WC, wc = wid % WC;

  const int g = (blockIdx.x & 7) * (gridDim.x >> 3) + (blockIdx.x >> 3);
  const int z = g / (mt * nt);
  const int rem = g - z * (mt * nt);
  const int ty = rem / nt, tx = rem - ty * nt;

  const u64 aOff = (u64)(z & aMask) * aStride;
  const u64 bOff = (u64)z * bStride;
  const float* gAf = nullptr;
  const u16* gA = nullptr;
  const u16* gAl = nullptr;
  if constexpr (AF32) {
    gAf = (const float*)Ap + aOff + (u64)ty * (u32)BM * (u32)K;
  } else {
    gA = (const u16*)Ap + aOff + (u64)ty * (u32)BM * (u32)K;
    if constexpr (X3) gAl = Aploi + aOff + (u64)ty * (u32)BM * (u32)K;
  }
  const float* gBf = nullptr;
  const u16* gB = nullptr;
  const u16* gBl = nullptr;
  if constexpr (BF32) {
    gBf = (const float*)Bp + bOff + (u64)tx * (u32)BN * (u32)K;
  } else {
    gB = (const u16*)Bp + bOff + (u64)tx * (u32)BN * (u32)K;
    if constexpr (X3) gBl = Bploi + bOff + (u64)tx * (u32)BN * (u32)K;
  }

  u64 aG[CA]; u32 aLd[CA];
#pragma unroll
  for (int i = 0; i < CA; ++i) {
    const int c = i * NTHR + tid;
    if constexpr (AF32) {
      const int row = c / 9, cc = c - row * 9;
      aG[i] = (row < BM && cc < 8) ? ((u64)row * (u32)K + (u32)(cc * 4)) : 0;
      aLd[i] = c * 8;
    } else {
      const int row = c >> 2, ks = c & 3;
      aG[i] = (u64)row * (u32)K + (u32)((ks ^ ((row >> 1) & 3)) << 3);
      aLd[i] = c << 3;
    }
  }
  u64 bG[CB]; u32 bLd[CB];
#pragma unroll
  for (int i = 0; i < CB; ++i) {
    const int c = i * NTHR + tid;
    if constexpr (BF32) {
      const int row = c / 9, cc = c - row * 9;
      bG[i] = (row < BN && cc < 8) ? ((u64)row * (u32)K + (u32)(cc * 4)) : 0;
      bLd[i] = c * 8;
    } else {
      const int row = c >> 2, ks = c & 3;
      bG[i] = (u64)row * (u32)K + (u32)((ks ^ ((row >> 1) & 3)) << 3);
      bLd[i] = c << 3;
    }
  }

  f32x4 acc[FM][FN];
#pragma unroll
  for (int m = 0; m < FM; ++m)
#pragma unroll
    for (int n = 0; n < FN; ++n) acc[m][n] = (f32x4){0.f, 0.f, 0.f, 0.f};

  auto STAGE = [&](int bufU, int k0) {
#pragma unroll
    for (int i = 0; i < CA; ++i) {
      if constexpr (AF32) {
        gload16(gAf + aG[i] + (u32)k0, &lds[bufU + aLd[i]]);
      } else {
        gload16(gA + aG[i] + (u32)k0, &lds[bufU + aLd[i]]);
        if constexpr (X3) gload16(gAl + aG[i] + (u32)k0, &lds[bufU + AL0 + aLd[i]]);
      }
    }
#pragma unroll
    for (int i = 0; i < CB; ++i) {
      if constexpr (BF32) {
        gload16(gBf + bG[i] + (u32)k0, &lds[bufU + A_SZ + bLd[i]]);
      } else {
        gload16(gB + bG[i] + (u32)k0, &lds[bufU + A_SZ + bLd[i]]);
        if constexpr (X3) gload16(gBl + bG[i] + (u32)k0, &lds[bufU + A_SZ + BL0 + bLd[i]]);
      }
    }
  };

  const int swz = (((lane >> 1) & 3) ^ (lane >> 4)) << 3;
  auto COMPUTE = [&](int bufU) {
    bfrag ah[FM], al[FM], bh[FN], bl[FN];
#pragma unroll
    for (int m = 0; m < FM; ++m) {
      const int row = wr * (FM * 16) + m * 16 + (lane & 15);
      if constexpr (AF32) {
        const u32 base = bufU + (u32)row * 72 + (u32)(lane >> 4) * 16;
        f32x4 p0 = *reinterpret_cast<const f32x4*>(&lds[base]);
        f32x4 p1 = *reinterpret_cast<const f32x4*>(&lds[base + 8]);
#pragma unroll
        for (int j = 0; j < 8; ++j) {
          float f = j < 4 ? p0[j] : p1[j - 4];
          __bf16 h = (__bf16)f;
          ah[m][j] = h;
          al[m][j] = (__bf16)(f - (float)h);
        }
      } else {
        const int idx = bufU + row * 32 + swz;
        ah[m] = *reinterpret_cast<const bfrag*>(&lds[idx]);
        if constexpr (X3) al[m] = *reinterpret_cast<const bfrag*>(&lds[idx + AL0]);
      }
    }
#pragma unroll
    for (int n = 0; n < FN; ++n) {
      const int row = wc * (FN * 16) + n * 16 + (lane & 15);
      if constexpr (BF32) {
        const u32 base = bufU + A_SZ + (u32)row * 72 + (u32)(lane >> 4) * 16;
        f32x4 p0 = *reinterpret_cast<const f32x4*>(&lds[base]);
        f32x4 p1 = *reinterpret_cast<const f32x4*>(&lds[base + 8]);
#pragma unroll
        for (int j = 0; j < 8; ++j) {
          float f = j < 4 ? p0[j] : p1[j - 4];
          __bf16 h = (__bf16)f;
          bh[n][j] = h;
          bl[n][j] = (__bf16)(f - (float)h);
        }
      } else {
        const int idx = bufU + A_SZ + row * 32 + swz;
        bh[n] = *reinterpret_cast<const bfrag*>(&lds[idx]);
        if constexpr (X3) bl[n] = *reinterpret_cast<const bfrag*>(&lds[idx + BL0]);
      }
    }
#pragma unroll
    for (int m = 0; m < FM; ++m)
#pragma unroll
      for (int n = 0; n < FN; ++n) {
        acc[m][n] = __builtin_amdgcn_mfma_f32_16x16x32_bf16(ah[m], bh[n], acc[m][n], 0, 0, 0);
        if constexpr (X3) {
          acc[m][n] = __builtin_amdgcn_mfma_f32_16x16x32_bf16(ah[m], bl[n], acc[m][n], 0, 0, 0);
          acc[m][n] = __builtin_amdgcn_mfma_f32_16x16x32_bf16(al[m], bh[n], acc[m][n], 0, 0, 0);
        }
      }
  };

  // transpose-write this block's 8-row r-slice of the staged f32 B-tile as
  // bf16 into KvtOut[z][k0+rl][tx*BN+s].  Threads 0..127 (waves 0-1) only;
  // LDS reads bank-rotated (2-way max); 16B global stores, 256B/16-lane runs.
  auto SIDEWRITE = [&](int bufU, int k0) {
    if (tid < 128) {
      const int rl = (ty << 3) + (tid >> 4);
      const int s8 = (tid & 15) << 3;
      const int rot = tid & 7;
      u32 pk[4];
      u16 val[8];
#pragma unroll
      for (int j = 0; j < 8; ++j) {
        const int je = (j + rot) & 7;
        const float f = *reinterpret_cast<const float*>(
            &lds[bufU + A_SZ + (u32)(s8 + je) * 72 + (u32)rl * 2]);
        val[je] = f2bf(f);
      }
#pragma unroll
      for (int j = 0; j < 4; ++j) pk[j] = (u32)val[2 * j] | ((u32)val[2 * j + 1] << 16);
      const u64 o = (u64)z * ((u64)K * 512) + (u64)(k0 + rl) * 512 + (u32)(tx * BN + s8);
      *reinterpret_cast<uint4*>(KvtOut + o) = make_uint4(pk[0], pk[1], pk[2], pk[3]);
    }
  };

  const int NT = K >> 5;
  STAGE(0, 0);
  asm volatile("s_waitcnt vmcnt(0)" ::: "memory");
  __builtin_amdgcn_s_barrier();
  int buf = 0;
  for (int t = 0; t < NT; ++t) {
    if (t + 1 < NT) STAGE(TILE - buf, (t + 1) << 5);
    if constexpr (WRKVT) SIDEWRITE(buf, t << 5);
    COMPUTE(buf);
    if (t + 1 < NT) {
      asm volatile("s_waitcnt vmcnt(0)" ::: "memory");
      __builtin_amdgcn_s_barrier();
      buf = TILE - buf;
    }
  }

  const u64 cOff = (u64)z * cStride;
  const u64 mOff = (u64)(z & aMask) * cStride;
  const int rB = ty * BM + wr * (FM * 16) + (lane >> 4) * 4;
  const int cB = tx * BN + wc * (FN * 16) + (lane & 15);
#pragma unroll
  for (int m = 0; m < FM; ++m)
#pragma unroll
    for (int n = 0; n < FN; ++n)
#pragma unroll
      for (int j = 0; j < 4; ++j) {
        const int rr = rB + m * 16 + j, cc = cB + n * 16;
        const u64 ci = cOff + (u64)rr * (u32)N + (u32)cc;
        float v = acc[m][n][j];
        if constexpr (ADDMASK) v += Mask[mOff + (u64)rr * (u32)N + (u32)cc];
        if constexpr (SPLITOUT) {
          u16 h = f2bf(v);
          Chi[ci] = h;
          Clo[ci] = f2bf(v - bf2f(h));
        } else {
          Cf[ci] = v;
        }
      }
}

// --------- softmax over s (one wave per row), fp32 in (mask pre-added) -------
__global__ __launch_bounds__(256) void k_softmax(const float* __restrict__ sc,
                                                 u16* __restrict__ attn) {
  const int row = blockIdx.x * 4 + (threadIdx.x >> 6);
  const int lane = threadIdx.x & 63;
  const float* srow = sc + (u64)row * 512 + lane * 8;
  float4 s0 = *reinterpret_cast<const float4*>(srow);
  float4 s1 = *reinterpret_cast<const float4*>(srow + 4);
  float x[8] = {s0.x, s0.y, s0.z, s0.w, s1.x, s1.y, s1.z, s1.w};
  float mx = x[0];
#pragma unroll
  for (int j = 1; j < 8; ++j) mx = fmaxf(mx, x[j]);
#pragma unroll
  for (int off = 32; off > 0; off >>= 1) mx = fmaxf(mx, __shfl_xor(mx, off));
  float sum = 0.f;
#pragma unroll
  for (int j = 0; j < 8; ++j) {
    x[j] = __expf(x[j] - mx);
    sum += x[j];
  }
#pragma unroll
  for (int off = 32; off > 0; off >>= 1) sum += __shfl_xor(sum, off);
  const float inv = 1.f / sum;
  u32 o[4];
#pragma unroll
  for (int j = 0; j < 4; ++j) {
    u16 e0 = f2bf(x[2 * j] * inv), e1 = f2bf(x[2 * j + 1] * inv);
    o[j] = (u32)e0 | ((u32)e1 << 16);
  }
  *reinterpret_cast<uint4*>(attn + (u64)row * 512 + lane * 8) = make_uint4(o[0], o[1], o[2], o[3]);
}

// -----------------------------------------------------------------------------
extern "C" void kernel_launch(void* const* d_in, const int* in_sizes, int n_in,
                              void* d_out, int out_size, void* d_ws, size_t ws_size,
                              hipStream_t stream) {
  // N=4, B=8, T=512, S=512, E=1024, R=1024
  const float* q = (const float*)d_in[0];
  const float* kvs = (const float*)d_in[1];
  const float* mask = (const float*)d_in[2];
  const float* Wk = (const float*)d_in[3];  // bk unused (constant over s)
  float* out = (float*)d_out;

  char* w = (char*)d_ws;
  u16* attn = (u16*)(w + 0);
  u16* wkt_hi = (u16*)(w + 16777216);
  u16* wkt_lo = (u16*)(w + 18874368);
  u16* qp_hi = (u16*)(w + 20971520);
  u16* qp_lo = (u16*)(w + 29360128);
  u16* kvt_hi = (u16*)(w + 104857600);
  float* sc = (float*)(w + 138412032);

  // 1) Wk [e][r] -> transposed split wkt[r][e] hi/lo
  k_trsplit64<0, 1, 1><<<dim3(16, 16, 1), dim3(256), 0, stream>>>(
      Wk, (u16*)nullptr, (u16*)nullptr, wkt_hi, wkt_lo, 1024, 1024);
  // 2) qproj[bt][r] = q[bt][e]*wkt[r][e]; A raw f32 (in-reg split), x3, split-out
  k_gemmF<1, 1, 0, 4, 4, 2, 2, 0, 1, 0><<<dim3(256), dim3(256), 0, stream>>>(
      q, (const u16*)nullptr, wkt_hi, wkt_lo,
      (float*)nullptr, qp_hi, qp_lo, (const float*)nullptr, (u16*)nullptr,
      1024, 1024, 32, 8, (u64)0, 0, (u64)0, (u64)0);
  // 3) scores[z][t][s] = qp[b][t][r]*kvs[z][s][r] + mask; B raw f32 (in-reg
  //    split), x3; side-writes kvt_hi[z][r][s] from the staged B-tiles
  k_gemmF<1, 0, 1, 4, 4, 2, 2, 1, 0, 1><<<dim3(512), dim3(256), 0, stream>>>(
      qp_hi, qp_lo, kvs, (const u16*)nullptr,
      sc, (u16*)nullptr, (u16*)nullptr, mask, kvt_hi,
      1024, 512, 4, 4, (u64)524288, 7, (u64)524288, (u64)262144);
  // 4) softmax(sc) -> attn bf16
  k_softmax<<<dim3(4096), dim3(256), 0, stream>>>(sc, attn);
  // 5) out[z][t][r] = attn[z][t][s]*kvt[z][r][s]; bf16 x1; 256x128, 512 blocks
  k_gemmF<0, 0, 0, 8, 4, 2, 2, 0, 0, 0><<<dim3(512), dim3(256), 0, stream>>>(
      attn, (const u16*)nullptr, kvt_hi, (const u16*)nullptr,
      out, (u16*)nullptr, (u16*)nullptr, (const float*)nullptr, (u16*)nullptr,
      512, 1024, 2, 8, (u64)262144, 31, (u64)524288, (u64)524288);

  (void)in_sizes; (void)n_in; (void)out_size; (void)ws_size;
}

// Round 10
// 159.981 us; speedup vs baseline: 1.0746x; 1.0116x over previous
//
#include <hip/hip_runtime.h>

typedef unsigned short u16;
typedef unsigned int u32;
typedef unsigned long long u64;

typedef __bf16 bfrag __attribute__((ext_vector_type(8)));
typedef float f32x4 __attribute__((ext_vector_type(4)));

typedef __attribute__((address_space(1))) char* gas1_p;
typedef __attribute__((address_space(3))) char* las3_p;

#define DI __device__ __forceinline__

DI u16 f2bf(float f) {
  u32 u = __float_as_uint(f);
  u += 0x7FFFu + ((u >> 16) & 1u);
  return (u16)(u >> 16);
}
DI float bf2f(u16 h) { return __uint_as_float(((u32)h) << 16); }

DI void gload16(const void* g, void* l) {
  __builtin_amdgcn_global_load_lds((gas1_p)(u64)g, (las3_p)(u32)(u64)l, 16, 0, 0);
}

// ------- 64x64 tile: straight split (hi/lo) and/or transposed (thi/tlo) ------
template <int WH, int WTH, int WTL>
__global__ __launch_bounds__(256) void k_trsplit64(const float* __restrict__ in,
                                                   u16* __restrict__ hi, u16* __restrict__ lo,
                                                   u16* __restrict__ thi, u16* __restrict__ tlo,
                                                   int rows, int cols) {
  __shared__ float tile[64][65];
  const u64 zoff = (u64)blockIdx.z * (u64)rows * (u64)cols;
  const int r0 = threadIdx.x >> 4;
  const int c4 = (threadIdx.x & 15) << 2;
  const float* src = in + zoff + (u64)(blockIdx.y * 64 + r0) * cols + blockIdx.x * 64 + c4;
#pragma unroll
  for (int p = 0; p < 4; ++p) {
    float4 v = *reinterpret_cast<const float4*>(src + (u64)(p * 16) * cols);
    tile[r0 + p * 16][c4 + 0] = v.x;
    tile[r0 + p * 16][c4 + 1] = v.y;
    tile[r0 + p * 16][c4 + 2] = v.z;
    tile[r0 + p * 16][c4 + 3] = v.w;
  }
  __syncthreads();
  if constexpr (WH) {
    const int rr = threadIdx.x >> 3;
    const int cc = (threadIdx.x & 7) << 3;
#pragma unroll
    for (int p = 0; p < 2; ++p) {
      const int r = rr + p * 32;
      u32 h[4], l[4];
#pragma unroll
      for (int j = 0; j < 4; ++j) {
        float a = tile[r][cc + 2 * j], b = tile[r][cc + 2 * j + 1];
        u16 ha = f2bf(a), hb = f2bf(b);
        h[j] = (u32)ha | ((u32)hb << 16);
        l[j] = (u32)f2bf(a - bf2f(ha)) | ((u32)f2bf(b - bf2f(hb)) << 16);
      }
      const u64 o = zoff + (u64)(blockIdx.y * 64 + r) * cols + blockIdx.x * 64 + cc;
      *reinterpret_cast<uint4*>(hi + o) = make_uint4(h[0], h[1], h[2], h[3]);
      *reinterpret_cast<uint4*>(lo + o) = make_uint4(l[0], l[1], l[2], l[3]);
    }
  }
  if constexpr (WTH) {
#pragma unroll
    for (int p = 0; p < 2; ++p) {
      const int id = threadIdx.x + p * 256;
      const int col = id >> 3;
      const int s8 = (id & 7) << 3;
      u32 h[4], l[4];
#pragma unroll
      for (int j = 0; j < 4; ++j) {
        float a = tile[s8 + 2 * j][col], b = tile[s8 + 2 * j + 1][col];
        u16 ha = f2bf(a), hb = f2bf(b);
        h[j] = (u32)ha | ((u32)hb << 16);
        if constexpr (WTL)
          l[j] = (u32)f2bf(a - bf2f(ha)) | ((u32)f2bf(b - bf2f(hb)) << 16);
      }
      const u64 o = zoff + (u64)(blockIdx.x * 64 + col) * rows + blockIdx.y * 64 + s8;
      *reinterpret_cast<uint4*>(thi + o) = make_uint4(h[0], h[1], h[2], h[3]);
      if constexpr (WTL)
        *reinterpret_cast<uint4*>(tlo + o) = make_uint4(l[0], l[1], l[2], l[3]);
    }
  }
}

// ===== unified 2-phase pipelined bt-GEMM: STAGE(next) || COMPUTE(cur) ========
// C[z][m][n] = sum_k A[z][m][k]*B[z][n][k].
// AF32/BF32: operand staged raw f32 (144B padded rows), in-register hi/lo split.
// X3: 3 MFMA passes (Ah*Bh + Ah*Bl + Al*Bh).  ADDMASK: +Mask.  SPLITOUT: hi/lo.
template <int X3, int AF32, int BF32, int FM, int FN, int WR, int WC,
          int ADDMASK, int SPLITOUT>
__global__ __launch_bounds__(WR * WC * 64, 2) void k_gemmF(
    const void* Ap, const u16* Aploi, const void* Bp, const u16* Bploi,
    float* __restrict__ Cf, u16* __restrict__ Chi, u16* __restrict__ Clo,
    const float* __restrict__ Mask,
    int K, int N, int mt, int nt,
    u64 aStride, int aMask, u64 bStride, u64 cStride) {
  constexpr int NTHR = WR * WC * 64;
  constexpr int BM = WR * FM * 16, BN = WC * FN * 16;
  constexpr int ACH = AF32 ? ((BM * 9 + NTHR - 1) / NTHR) * NTHR : BM * 4;
  constexpr int BCH = BF32 ? ((BN * 9 + NTHR - 1) / NTHR) * NTHR : BN * 4;
  constexpr int A_SZ = AF32 ? ACH * 8 : BM * 32 * (1 + X3);
  constexpr int B_SZ = BF32 ? BCH * 8 : BN * 32 * (1 + X3);
  constexpr int AL0 = BM * 32;
  constexpr int BL0 = BN * 32;
  constexpr int TILE = A_SZ + B_SZ;
  constexpr int CA = ACH / NTHR, CB = BCH / NTHR;
  __shared__ u16 lds[2 * TILE];

  const int tid = threadIdx.x, lane = tid & 63;
  const int wid = tid >> 6, wr = wid / WC, wc = wid % WC;

  const int g = (blockIdx.x & 7) * (gridDim.x >> 3) + (blockIdx.x >> 3);
  const int z = g / (mt * nt);
  const int rem = g - z * (mt * nt);
  const int ty = rem / nt, tx = rem - ty * nt;

  const u64 aOff = (u64)(z & aMask) * aStride;
  const u64 bOff = (u64)z * bStride;
  const float* gAf = nullptr;
  const u16* gA = nullptr;
  const u16* gAl = nullptr;
  if constexpr (AF32) {
    gAf = (const float*)Ap + aOff + (u64)ty * (u32)BM * (u32)K;
  } else {
    gA = (const u16*)Ap + aOff + (u64)ty * (u32)BM * (u32)K;
    if constexpr (X3) gAl = Aploi + aOff + (u64)ty * (u32)BM * (u32)K;
  }
  const float* gBf = nullptr;
  const u16* gB = nullptr;
  const u16* gBl = nullptr;
  if constexpr (BF32) {
    gBf = (const float*)Bp + bOff + (u64)tx * (u32)BN * (u32)K;
  } else {
    gB = (const u16*)Bp + bOff + (u64)tx * (u32)BN * (u32)K;
    if constexpr (X3) gBl = Bploi + bOff + (u64)tx * (u32)BN * (u32)K;
  }

  u64 aG[CA]; u32 aLd[CA];
#pragma unroll
  for (int i = 0; i < CA; ++i) {
    const int c = i * NTHR + tid;
    if constexpr (AF32) {
      const int row = c / 9, cc = c - row * 9;
      aG[i] = (row < BM && cc < 8) ? ((u64)row * (u32)K + (u32)(cc * 4)) : 0;
      aLd[i] = c * 8;
    } else {
      const int row = c >> 2, ks = c & 3;
      aG[i] = (u64)row * (u32)K + (u32)((ks ^ ((row >> 1) & 3)) << 3);
      aLd[i] = c << 3;
    }
  }
  u64 bG[CB]; u32 bLd[CB];
#pragma unroll
  for (int i = 0; i < CB; ++i) {
    const int c = i * NTHR + tid;
    if constexpr (BF32) {
      const int row = c / 9, cc = c - row * 9;
      bG[i] = (row < BN && cc < 8) ? ((u64)row * (u32)K + (u32)(cc * 4)) : 0;
      bLd[i] = c * 8;
    } else {
      const int row = c >> 2, ks = c & 3;
      bG[i] = (u64)row * (u32)K + (u32)((ks ^ ((row >> 1) & 3)) << 3);
      bLd[i] = c << 3;
    }
  }

  f32x4 acc[FM][FN];
#pragma unroll
  for (int m = 0; m < FM; ++m)
#pragma unroll
    for (int n = 0; n < FN; ++n) acc[m][n] = (f32x4){0.f, 0.f, 0.f, 0.f};

  auto STAGE = [&](int bufU, int k0) {
#pragma unroll
    for (int i = 0; i < CA; ++i) {
      if constexpr (AF32) {
        gload16(gAf + aG[i] + (u32)k0, &lds[bufU + aLd[i]]);
      } else {
        gload16(gA + aG[i] + (u32)k0, &lds[bufU + aLd[i]]);
        if constexpr (X3) gload16(gAl + aG[i] + (u32)k0, &lds[bufU + AL0 + aLd[i]]);
      }
    }
#pragma unroll
    for (int i = 0; i < CB; ++i) {
      if constexpr (BF32) {
        gload16(gBf + bG[i] + (u32)k0, &lds[bufU + A_SZ + bLd[i]]);
      } else {
        gload16(gB + bG[i] + (u32)k0, &lds[bufU + A_SZ + bLd[i]]);
        if constexpr (X3) gload16(gBl + bG[i] + (u32)k0, &lds[bufU + A_SZ + BL0 + bLd[i]]);
      }
    }
  };

  const int swz = (((lane >> 1) & 3) ^ (lane >> 4)) << 3;
  auto COMPUTE = [&](int bufU) {
    bfrag ah[FM], al[FM], bh[FN], bl[FN];
#pragma unroll
    for (int m = 0; m < FM; ++m) {
      const int row = wr * (FM * 16) + m * 16 + (lane & 15);
      if constexpr (AF32) {
        const u32 base = bufU + (u32)row * 72 + (u32)(lane >> 4) * 16;
        f32x4 p0 = *reinterpret_cast<const f32x4*>(&lds[base]);
        f32x4 p1 = *reinterpret_cast<const f32x4*>(&lds[base + 8]);
#pragma unroll
        for (int j = 0; j < 8; ++j) {
          float f = j < 4 ? p0[j] : p1[j - 4];
          __bf16 h = (__bf16)f;
          ah[m][j] = h;
          al[m][j] = (__bf16)(f - (float)h);
        }
      } else {
        const int idx = bufU + row * 32 + swz;
        ah[m] = *reinterpret_cast<const bfrag*>(&lds[idx]);
        if constexpr (X3) al[m] = *reinterpret_cast<const bfrag*>(&lds[idx + AL0]);
      }
    }
#pragma unroll
    for (int n = 0; n < FN; ++n) {
      const int row = wc * (FN * 16) + n * 16 + (lane & 15);
      if constexpr (BF32) {
        const u32 base = bufU + A_SZ + (u32)row * 72 + (u32)(lane >> 4) * 16;
        f32x4 p0 = *reinterpret_cast<const f32x4*>(&lds[base]);
        f32x4 p1 = *reinterpret_cast<const f32x4*>(&lds[base + 8]);
#pragma unroll
        for (int j = 0; j < 8; ++j) {
          float f = j < 4 ? p0[j] : p1[j - 4];
          __bf16 h = (__bf16)f;
          bh[n][j] = h;
          bl[n][j] = (__bf16)(f - (float)h);
        }
      } else {
        const int idx = bufU + A_SZ + row * 32 + swz;
        bh[n] = *reinterpret_cast<const bfrag*>(&lds[idx]);
        if constexpr (X3) bl[n] = *reinterpret_cast<const bfrag*>(&lds[idx + BL0]);
      }
    }
#pragma unroll
    for (int m = 0; m < FM; ++m)
#pragma unroll
      for (int n = 0; n < FN; ++n) {
        acc[m][n] = __builtin_amdgcn_mfma_f32_16x16x32_bf16(ah[m], bh[n], acc[m][n], 0, 0, 0);
        if constexpr (X3) {
          acc[m][n] = __builtin_amdgcn_mfma_f32_16x16x32_bf16(ah[m], bl[n], acc[m][n], 0, 0, 0);
          acc[m][n] = __builtin_amdgcn_mfma_f32_16x16x32_bf16(al[m], bh[n], acc[m][n], 0, 0, 0);
        }
      }
  };

  const int NT = K >> 5;
  STAGE(0, 0);
  asm volatile("s_waitcnt vmcnt(0)" ::: "memory");
  __builtin_amdgcn_s_barrier();
  int buf = 0;
  for (int t = 0; t < NT; ++t) {
    if (t + 1 < NT) STAGE(TILE - buf, (t + 1) << 5);
    COMPUTE(buf);
    if (t + 1 < NT) {
      asm volatile("s_waitcnt vmcnt(0)" ::: "memory");
      __builtin_amdgcn_s_barrier();
      buf = TILE - buf;
    }
  }

  const u64 cOff = (u64)z * cStride;
  const u64 mOff = (u64)(z & aMask) * cStride;
  const int rB = ty * BM + wr * (FM * 16) + (lane >> 4) * 4;
  const int cB = tx * BN + wc * (FN * 16) + (lane & 15);
#pragma unroll
  for (int m = 0; m < FM; ++m)
#pragma unroll
    for (int n = 0; n < FN; ++n)
#pragma unroll
      for (int j = 0; j < 4; ++j) {
        const int rr = rB + m * 16 + j, cc = cB + n * 16;
        const u64 ci = cOff + (u64)rr * (u32)N + (u32)cc;
        float v = acc[m][n][j];
        if constexpr (ADDMASK) v += Mask[mOff + (u64)rr * (u32)N + (u32)cc];
        if constexpr (SPLITOUT) {
          u16 h = f2bf(v);
          Chi[ci] = h;
          Clo[ci] = f2bf(v - bf2f(h));
        } else {
          Cf[ci] = v;
        }
      }
}

// --------- softmax over s (one wave per row), fp32 in (mask pre-added) -------
__global__ __launch_bounds__(256) void k_softmax(const float* __restrict__ sc,
                                                 u16* __restrict__ attn) {
  const int row = blockIdx.x * 4 + (threadIdx.x >> 6);
  const int lane = threadIdx.x & 63;
  const float* srow = sc + (u64)row * 512 + lane * 8;
  float4 s0 = *reinterpret_cast<const float4*>(srow);
  float4 s1 = *reinterpret_cast<const float4*>(srow + 4);
  float x[8] = {s0.x, s0.y, s0.z, s0.w, s1.x, s1.y, s1.z, s1.w};
  float mx = x[0];
#pragma unroll
  for (int j = 1; j < 8; ++j) mx = fmaxf(mx, x[j]);
#pragma unroll
  for (int off = 32; off > 0; off >>= 1) mx = fmaxf(mx, __shfl_xor(mx, off));
  float sum = 0.f;
#pragma unroll
  for (int j = 0; j < 8; ++j) {
    x[j] = __expf(x[j] - mx);
    sum += x[j];
  }
#pragma unroll
  for (int off = 32; off > 0; off >>= 1) sum += __shfl_xor(sum, off);
  const float inv = 1.f / sum;
  u32 o[4];
#pragma unroll
  for (int j = 0; j < 4; ++j) {
    u16 e0 = f2bf(x[2 * j] * inv), e1 = f2bf(x[2 * j + 1] * inv);
    o[j] = (u32)e0 | ((u32)e1 << 16);
  }
  *reinterpret_cast<uint4*>(attn + (u64)row * 512 + lane * 8) = make_uint4(o[0], o[1], o[2], o[3]);
}

// -----------------------------------------------------------------------------
extern "C" void kernel_launch(void* const* d_in, const int* in_sizes, int n_in,
                              void* d_out, int out_size, void* d_ws, size_t ws_size,
                              hipStream_t stream) {
  // N=4, B=8, T=512, S=512, E=1024, R=1024
  const float* q = (const float*)d_in[0];
  const float* kvs = (const float*)d_in[1];
  const float* mask = (const float*)d_in[2];
  const float* Wk = (const float*)d_in[3];  // bk unused (constant over s)
  float* out = (float*)d_out;

  char* w = (char*)d_ws;
  u16* attn = (u16*)(w + 0);
  u16* wkt_hi = (u16*)(w + 16777216);
  u16* wkt_lo = (u16*)(w + 18874368);
  u16* qp_hi = (u16*)(w + 20971520);
  u16* qp_lo = (u16*)(w + 29360128);
  u16* kvt_hi = (u16*)(w + 104857600);
  float* sc = (float*)(w + 138412032);

  // 1) Wk [e][r] -> transposed split wkt[r][e] hi/lo
  k_trsplit64<0, 1, 1><<<dim3(16, 16, 1), dim3(256), 0, stream>>>(
      Wk, (u16*)nullptr, (u16*)nullptr, wkt_hi, wkt_lo, 1024, 1024);
  // 2) kvs -> transposed hi: kvt[z][r][s]
  k_trsplit64<0, 1, 0><<<dim3(16, 8, 32), dim3(256), 0, stream>>>(
      kvs, (u16*)nullptr, (u16*)nullptr, kvt_hi, (u16*)nullptr, 512, 1024);
  // 3) qproj[bt][r] = q[bt][e]*wkt[r][e]; A raw f32 (in-reg split), x3, split-out
  k_gemmF<1, 1, 0, 4, 4, 2, 2, 0, 1><<<dim3(256), dim3(256), 0, stream>>>(
      q, (const u16*)nullptr, wkt_hi, wkt_lo,
      (float*)nullptr, qp_hi, qp_lo, (const float*)nullptr,
      1024, 1024, 32, 8, (u64)0, 0, (u64)0, (u64)0);
  // 4) scores[z][t][s] = qp[b][t][r]*kvs[z][s][r] + mask; B raw f32, x3
  k_gemmF<1, 0, 1, 4, 4, 2, 2, 1, 0><<<dim3(512), dim3(256), 0, stream>>>(
      qp_hi, qp_lo, kvs, (const u16*)nullptr,
      sc, (u16*)nullptr, (u16*)nullptr, mask,
      1024, 512, 4, 4, (u64)524288, 7, (u64)524288, (u64)262144);
  // 5) softmax(sc) -> attn bf16
  k_softmax<<<dim3(4096), dim3(256), 0, stream>>>(sc, attn);
  // 6) out[z][t][r] = attn[z][t][s]*kvt[z][r][s]; bf16 x1; 256x128, 512 blocks
  k_gemmF<0, 0, 0, 8, 4, 2, 2, 0, 0><<<dim3(512), dim3(256), 0, stream>>>(
      attn, (const u16*)nullptr, kvt_hi, (const u16*)nullptr,
      out, (u16*)nullptr, (u16*)nullptr, (const float*)nullptr,
      512, 1024, 2, 8, (u64)262144, 31, (u64)524288, (u64)524288);

  (void)in_sizes; (void)n_in; (void)out_size; (void)ws_size;
}

// Round 11
// 159.286 us; speedup vs baseline: 1.0793x; 1.0044x over previous
//
#include <hip/hip_runtime.h>

typedef unsigned short u16;
typedef unsigned int u32;
typedef unsigned long long u64;

typedef __bf16 bfrag __attribute__((ext_vector_type(8)));
typedef float f32x4 __attribute__((ext_vector_type(4)));

typedef __attribute__((address_space(1))) char* gas1_p;
typedef __attribute__((address_space(3))) char* las3_p;

#define DI __device__ __forceinline__

DI u16 f2bf(float f) {
  u32 u = __float_as_uint(f);
  u += 0x7FFFu + ((u >> 16) & 1u);
  return (u16)(u >> 16);
}
DI float bf2f(u16 h) { return __uint_as_float(((u32)h) << 16); }

DI void gload16(const void* g, void* l) {
  __builtin_amdgcn_global_load_lds((gas1_p)(u64)g, (las3_p)(u32)(u64)l, 16, 0, 0);
}

// ---------------- trsplit body: 64x64 tile transpose/split -------------------
template <int WH, int WTH, int WTL>
DI void trsplit_body(float (*tile)[65], int bx, int by, int bz,
                     const float* in, u16* hi, u16* lo, u16* thi, u16* tlo,
                     int rows, int cols) {
  const u64 zoff = (u64)bz * (u64)rows * (u64)cols;
  const int r0 = threadIdx.x >> 4;
  const int c4 = (threadIdx.x & 15) << 2;
  const float* src = in + zoff + (u64)(by * 64 + r0) * cols + bx * 64 + c4;
#pragma unroll
  for (int p = 0; p < 4; ++p) {
    float4 v = *reinterpret_cast<const float4*>(src + (u64)(p * 16) * cols);
    tile[r0 + p * 16][c4 + 0] = v.x;
    tile[r0 + p * 16][c4 + 1] = v.y;
    tile[r0 + p * 16][c4 + 2] = v.z;
    tile[r0 + p * 16][c4 + 3] = v.w;
  }
  __syncthreads();
  if constexpr (WH) {
    const int rr = threadIdx.x >> 3;
    const int cc = (threadIdx.x & 7) << 3;
#pragma unroll
    for (int p = 0; p < 2; ++p) {
      const int r = rr + p * 32;
      u32 h[4], l[4];
#pragma unroll
      for (int j = 0; j < 4; ++j) {
        float a = tile[r][cc + 2 * j], b = tile[r][cc + 2 * j + 1];
        u16 ha = f2bf(a), hb = f2bf(b);
        h[j] = (u32)ha | ((u32)hb << 16);
        l[j] = (u32)f2bf(a - bf2f(ha)) | ((u32)f2bf(b - bf2f(hb)) << 16);
      }
      const u64 o = zoff + (u64)(by * 64 + r) * cols + bx * 64 + cc;
      *reinterpret_cast<uint4*>(hi + o) = make_uint4(h[0], h[1], h[2], h[3]);
      *reinterpret_cast<uint4*>(lo + o) = make_uint4(l[0], l[1], l[2], l[3]);
    }
  }
  if constexpr (WTH) {
#pragma unroll
    for (int p = 0; p < 2; ++p) {
      const int id = threadIdx.x + p * 256;
      const int col = id >> 3;
      const int s8 = (id & 7) << 3;
      u32 h[4], l[4];
#pragma unroll
      for (int j = 0; j < 4; ++j) {
        float a = tile[s8 + 2 * j][col], b = tile[s8 + 2 * j + 1][col];
        u16 ha = f2bf(a), hb = f2bf(b);
        h[j] = (u32)ha | ((u32)hb << 16);
        if constexpr (WTL)
          l[j] = (u32)f2bf(a - bf2f(ha)) | ((u32)f2bf(b - bf2f(hb)) << 16);
      }
      const u64 o = zoff + (u64)(bx * 64 + col) * rows + by * 64 + s8;
      *reinterpret_cast<uint4*>(thi + o) = make_uint4(h[0], h[1], h[2], h[3]);
      if constexpr (WTL)
        *reinterpret_cast<uint4*>(tlo + o) = make_uint4(l[0], l[1], l[2], l[3]);
    }
  }
}

template <int WH, int WTH, int WTL>
__global__ __launch_bounds__(256) void k_trsplit64(const float* __restrict__ in,
                                                   u16* __restrict__ hi, u16* __restrict__ lo,
                                                   u16* __restrict__ thi, u16* __restrict__ tlo,
                                                   int rows, int cols) {
  __shared__ float tile[64][65];
  trsplit_body<WH, WTH, WTL>(tile, blockIdx.x, blockIdx.y, blockIdx.z,
                             in, hi, lo, thi, tlo, rows, cols);
}

// ===== 2-phase pipelined bt-GEMM body (R6/R10-proven) ========================
template <int X3, int AF32, int BF32, int FM, int FN, int WR, int WC>
constexpr int tile_u16() {
  constexpr int NTHR = WR * WC * 64;
  constexpr int BM = WR * FM * 16, BN = WC * FN * 16;
  constexpr int ACH = AF32 ? ((BM * 9 + NTHR - 1) / NTHR) * NTHR : BM * 4;
  constexpr int BCH = BF32 ? ((BN * 9 + NTHR - 1) / NTHR) * NTHR : BN * 4;
  constexpr int A_SZ = AF32 ? ACH * 8 : BM * 32 * (1 + X3);
  constexpr int B_SZ = BF32 ? BCH * 8 : BN * 32 * (1 + X3);
  return A_SZ + B_SZ;
}

template <int X3, int AF32, int BF32, int FM, int FN, int WR, int WC,
          int ADDMASK, int SPLITOUT>
DI void gemmF_body(u16* lds, int gblk, int ngrid,
                   const void* Ap, const u16* Aploi, const void* Bp, const u16* Bploi,
                   float* Cf, u16* Chi, u16* Clo, const float* Mask,
                   int K, int N, int mt, int nt,
                   u64 aStride, int aMask, u64 bStride, u64 cStride) {
  constexpr int NTHR = WR * WC * 64;
  constexpr int BM = WR * FM * 16, BN = WC * FN * 16;
  constexpr int ACH = AF32 ? ((BM * 9 + NTHR - 1) / NTHR) * NTHR : BM * 4;
  constexpr int BCH = BF32 ? ((BN * 9 + NTHR - 1) / NTHR) * NTHR : BN * 4;
  constexpr int A_SZ = AF32 ? ACH * 8 : BM * 32 * (1 + X3);
  constexpr int B_SZ = BF32 ? BCH * 8 : BN * 32 * (1 + X3);
  constexpr int AL0 = BM * 32;
  constexpr int BL0 = BN * 32;
  constexpr int TILE = A_SZ + B_SZ;
  constexpr int CA = ACH / NTHR, CB = BCH / NTHR;

  const int tid = threadIdx.x, lane = tid & 63;
  const int wid = tid >> 6, wr = wid / WC, wc = wid % WC;

  const int g = (gblk & 7) * (ngrid >> 3) + (gblk >> 3);
  const int z = g / (mt * nt);
  const int rem = g - z * (mt * nt);
  const int ty = rem / nt, tx = rem - ty * nt;

  const u64 aOff = (u64)(z & aMask) * aStride;
  const u64 bOff = (u64)z * bStride;
  const float* gAf = nullptr;
  const u16* gA = nullptr;
  const u16* gAl = nullptr;
  if constexpr (AF32) {
    gAf = (const float*)Ap + aOff + (u64)ty * (u32)BM * (u32)K;
  } else {
    gA = (const u16*)Ap + aOff + (u64)ty * (u32)BM * (u32)K;
    if constexpr (X3) gAl = Aploi + aOff + (u64)ty * (u32)BM * (u32)K;
  }
  const float* gBf = nullptr;
  const u16* gB = nullptr;
  const u16* gBl = nullptr;
  if constexpr (BF32) {
    gBf = (const float*)Bp + bOff + (u64)tx * (u32)BN * (u32)K;
  } else {
    gB = (const u16*)Bp + bOff + (u64)tx * (u32)BN * (u32)K;
    if constexpr (X3) gBl = Bploi + bOff + (u64)tx * (u32)BN * (u32)K;
  }

  u64 aG[CA]; u32 aLd[CA];
#pragma unroll
  for (int i = 0; i < CA; ++i) {
    const int c = i * NTHR + tid;
    if constexpr (AF32) {
      const int row = c / 9, cc = c - row * 9;
      aG[i] = (row < BM && cc < 8) ? ((u64)row * (u32)K + (u32)(cc * 4)) : 0;
      aLd[i] = c * 8;
    } else {
      const int row = c >> 2, ks = c & 3;
      aG[i] = (u64)row * (u32)K + (u32)((ks ^ ((row >> 1) & 3)) << 3);
      aLd[i] = c << 3;
    }
  }
  u64 bG[CB]; u32 bLd[CB];
#pragma unroll
  for (int i = 0; i < CB; ++i) {
    const int c = i * NTHR + tid;
    if constexpr (BF32) {
      const int row = c / 9, cc = c - row * 9;
      bG[i] = (row < BN && cc < 8) ? ((u64)row * (u32)K + (u32)(cc * 4)) : 0;
      bLd[i] = c * 8;
    } else {
      const int row = c >> 2, ks = c & 3;
      bG[i] = (u64)row * (u32)K + (u32)((ks ^ ((row >> 1) & 3)) << 3);
      bLd[i] = c << 3;
    }
  }

  f32x4 acc[FM][FN];
#pragma unroll
  for (int m = 0; m < FM; ++m)
#pragma unroll
    for (int n = 0; n < FN; ++n) acc[m][n] = (f32x4){0.f, 0.f, 0.f, 0.f};

  auto STAGE = [&](int bufU, int k0) {
#pragma unroll
    for (int i = 0; i < CA; ++i) {
      if constexpr (AF32) {
        gload16(gAf + aG[i] + (u32)k0, &lds[bufU + aLd[i]]);
      } else {
        gload16(gA + aG[i] + (u32)k0, &lds[bufU + aLd[i]]);
        if constexpr (X3) gload16(gAl + aG[i] + (u32)k0, &lds[bufU + AL0 + aLd[i]]);
      }
    }
#pragma unroll
    for (int i = 0; i < CB; ++i) {
      if constexpr (BF32) {
        gload16(gBf + bG[i] + (u32)k0, &lds[bufU + A_SZ + bLd[i]]);
      } else {
        gload16(gB + bG[i] + (u32)k0, &lds[bufU + A_SZ + bLd[i]]);
        if constexpr (X3) gload16(gBl + bG[i] + (u32)k0, &lds[bufU + A_SZ + BL0 + bLd[i]]);
      }
    }
  };

  const int swz = (((lane >> 1) & 3) ^ (lane >> 4)) << 3;
  auto COMPUTE = [&](int bufU) {
    bfrag ah[FM], al[FM], bh[FN], bl[FN];
#pragma unroll
    for (int m = 0; m < FM; ++m) {
      const int row = wr * (FM * 16) + m * 16 + (lane & 15);
      if constexpr (AF32) {
        const u32 base = bufU + (u32)row * 72 + (u32)(lane >> 4) * 16;
        f32x4 p0 = *reinterpret_cast<const f32x4*>(&lds[base]);
        f32x4 p1 = *reinterpret_cast<const f32x4*>(&lds[base + 8]);
#pragma unroll
        for (int j = 0; j < 8; ++j) {
          float f = j < 4 ? p0[j] : p1[j - 4];
          __bf16 h = (__bf16)f;
          ah[m][j] = h;
          al[m][j] = (__bf16)(f - (float)h);
        }
      } else {
        const int idx = bufU + row * 32 + swz;
        ah[m] = *reinterpret_cast<const bfrag*>(&lds[idx]);
        if constexpr (X3) al[m] = *reinterpret_cast<const bfrag*>(&lds[idx + AL0]);
      }
    }
#pragma unroll
    for (int n = 0; n < FN; ++n) {
      const int row = wc * (FN * 16) + n * 16 + (lane & 15);
      if constexpr (BF32) {
        const u32 base = bufU + A_SZ + (u32)row * 72 + (u32)(lane >> 4) * 16;
        f32x4 p0 = *reinterpret_cast<const f32x4*>(&lds[base]);
        f32x4 p1 = *reinterpret_cast<const f32x4*>(&lds[base + 8]);
#pragma unroll
        for (int j = 0; j < 8; ++j) {
          float f = j < 4 ? p0[j] : p1[j - 4];
          __bf16 h = (__bf16)f;
          bh[n][j] = h;
          bl[n][j] = (__bf16)(f - (float)h);
        }
      } else {
        const int idx = bufU + A_SZ + row * 32 + swz;
        bh[n] = *reinterpret_cast<const bfrag*>(&lds[idx]);
        if constexpr (X3) bl[n] = *reinterpret_cast<const bfrag*>(&lds[idx + BL0]);
      }
    }
#pragma unroll
    for (int m = 0; m < FM; ++m)
#pragma unroll
      for (int n = 0; n < FN; ++n) {
        acc[m][n] = __builtin_amdgcn_mfma_f32_16x16x32_bf16(ah[m], bh[n], acc[m][n], 0, 0, 0);
        if constexpr (X3) {
          acc[m][n] = __builtin_amdgcn_mfma_f32_16x16x32_bf16(ah[m], bl[n], acc[m][n], 0, 0, 0);
          acc[m][n] = __builtin_amdgcn_mfma_f32_16x16x32_bf16(al[m], bh[n], acc[m][n], 0, 0, 0);
        }
      }
  };

  const int NT = K >> 5;
  STAGE(0, 0);
  asm volatile("s_waitcnt vmcnt(0)" ::: "memory");
  __builtin_amdgcn_s_barrier();
  int buf = 0;
  for (int t = 0; t < NT; ++t) {
    if (t + 1 < NT) STAGE(TILE - buf, (t + 1) << 5);
    COMPUTE(buf);
    if (t + 1 < NT) {
      asm volatile("s_waitcnt vmcnt(0)" ::: "memory");
      __builtin_amdgcn_s_barrier();
      buf = TILE - buf;
    }
  }

  const u64 cOff = (u64)z * cStride;
  const u64 mOff = (u64)(z & aMask) * cStride;
  const int rB = ty * BM + wr * (FM * 16) + (lane >> 4) * 4;
  const int cB = tx * BN + wc * (FN * 16) + (lane & 15);
#pragma unroll
  for (int m = 0; m < FM; ++m)
#pragma unroll
    for (int n = 0; n < FN; ++n)
#pragma unroll
      for (int j = 0; j < 4; ++j) {
        const int rr = rB + m * 16 + j, cc = cB + n * 16;
        const u64 ci = cOff + (u64)rr * (u32)N + (u32)cc;
        float v = acc[m][n][j];
        if constexpr (ADDMASK) v += Mask[mOff + (u64)rr * (u32)N + (u32)cc];
        if constexpr (SPLITOUT) {
          u16 h = f2bf(v);
          Chi[ci] = h;
          Clo[ci] = f2bf(v - bf2f(h));
        } else {
          Cf[ci] = v;
        }
      }
}

// standalone GEMM kernel wrapper (scores, PV)
template <int X3, int AF32, int BF32, int FM, int FN, int WR, int WC,
          int ADDMASK, int SPLITOUT>
__global__ __launch_bounds__(WR * WC * 64, 2) void k_gemmF(
    const void* Ap, const u16* Aploi, const void* Bp, const u16* Bploi,
    float* __restrict__ Cf, u16* __restrict__ Chi, u16* __restrict__ Clo,
    const float* __restrict__ Mask,
    int K, int N, int mt, int nt,
    u64 aStride, int aMask, u64 bStride, u64 cStride) {
  __shared__ u16 lds[2 * tile_u16<X3, AF32, BF32, FM, FN, WR, WC>()];
  gemmF_body<X3, AF32, BF32, FM, FN, WR, WC, ADDMASK, SPLITOUT>(
      lds, blockIdx.x, gridDim.x, Ap, Aploi, Bp, Bploi, Cf, Chi, Clo, Mask,
      K, N, mt, nt, aStride, aMask, bStride, cStride);
}

// ===== fat kernel: qproj (blocks 0..255, compute-bound, 1 block/CU) =========
// ===== + kvs transpose (blocks 256..4351, BW-bound, fills second CU slot) ====
// Independent work; trsplit streams HBM in the CU slot qproj leaves empty.
__global__ __launch_bounds__(256, 2) void k_qproj_trsplit(
    const float* __restrict__ q, const u16* __restrict__ wkt_hi,
    const u16* __restrict__ wkt_lo, u16* __restrict__ qp_hi,
    u16* __restrict__ qp_lo, const float* __restrict__ kvs,
    u16* __restrict__ kvt_hi) {
  __shared__ __align__(16) char smem[2 * tile_u16<1, 1, 0, 4, 4, 2, 2>() * 2];
  if (blockIdx.x < 256) {
    gemmF_body<1, 1, 0, 4, 4, 2, 2, 0, 1>(
        (u16*)smem, blockIdx.x, 256, q, (const u16*)nullptr, wkt_hi, wkt_lo,
        (float*)nullptr, qp_hi, qp_lo, (const float*)nullptr,
        1024, 1024, 32, 8, (u64)0, 0, (u64)0, (u64)0);
  } else {
    const int idx = blockIdx.x - 256;  // 4096 tiles: (16 x, 8 y, 32 z)
    trsplit_body<0, 1, 0>((float(*)[65])smem, idx & 15, (idx >> 4) & 7, idx >> 7,
                          kvs, (u16*)nullptr, (u16*)nullptr, kvt_hi, (u16*)nullptr,
                          512, 1024);
  }
}

// --------- softmax over s (one wave per row), fp32 in (mask pre-added) -------
__global__ __launch_bounds__(256) void k_softmax(const float* __restrict__ sc,
                                                 u16* __restrict__ attn) {
  const int row = blockIdx.x * 4 + (threadIdx.x >> 6);
  const int lane = threadIdx.x & 63;
  const float* srow = sc + (u64)row * 512 + lane * 8;
  float4 s0 = *reinterpret_cast<const float4*>(srow);
  float4 s1 = *reinterpret_cast<const float4*>(srow + 4);
  float x[8] = {s0.x, s0.y, s0.z, s0.w, s1.x, s1.y, s1.z, s1.w};
  float mx = x[0];
#pragma unroll
  for (int j = 1; j < 8; ++j) mx = fmaxf(mx, x[j]);
#pragma unroll
  for (int off = 32; off > 0; off >>= 1) mx = fmaxf(mx, __shfl_xor(mx, off));
  float sum = 0.f;
#pragma unroll
  for (int j = 0; j < 8; ++j) {
    x[j] = __expf(x[j] - mx);
    sum += x[j];
  }
#pragma unroll
  for (int off = 32; off > 0; off >>= 1) sum += __shfl_xor(sum, off);
  const float inv = 1.f / sum;
  u32 o[4];
#pragma unroll
  for (int j = 0; j < 4; ++j) {
    u16 e0 = f2bf(x[2 * j] * inv), e1 = f2bf(x[2 * j + 1] * inv);
    o[j] = (u32)e0 | ((u32)e1 << 16);
  }
  *reinterpret_cast<uint4*>(attn + (u64)row * 512 + lane * 8) = make_uint4(o[0], o[1], o[2], o[3]);
}

// -----------------------------------------------------------------------------
extern "C" void kernel_launch(void* const* d_in, const int* in_sizes, int n_in,
                              void* d_out, int out_size, void* d_ws, size_t ws_size,
                              hipStream_t stream) {
  // N=4, B=8, T=512, S=512, E=1024, R=1024
  const float* q = (const float*)d_in[0];
  const float* kvs = (const float*)d_in[1];
  const float* mask = (const float*)d_in[2];
  const float* Wk = (const float*)d_in[3];  // bk unused (constant over s)
  float* out = (float*)d_out;

  char* w = (char*)d_ws;
  u16* attn = (u16*)(w + 0);
  u16* wkt_hi = (u16*)(w + 16777216);
  u16* wkt_lo = (u16*)(w + 18874368);
  u16* qp_hi = (u16*)(w + 20971520);
  u16* qp_lo = (u16*)(w + 29360128);
  u16* kvt_hi = (u16*)(w + 104857600);
  float* sc = (float*)(w + 138412032);

  // 1) Wk [e][r] -> transposed split wkt[r][e] hi/lo
  k_trsplit64<0, 1, 1><<<dim3(16, 16, 1), dim3(256), 0, stream>>>(
      Wk, (u16*)nullptr, (u16*)nullptr, wkt_hi, wkt_lo, 1024, 1024);
  // 2) fused: qproj (blocks 0-255) + kvs->kvt transpose (blocks 256-4351)
  k_qproj_trsplit<<<dim3(4352), dim3(256), 0, stream>>>(
      q, wkt_hi, wkt_lo, qp_hi, qp_lo, kvs, kvt_hi);
  // 3) scores[z][t][s] = qp[b][t][r]*kvs[z][s][r] + mask; B raw f32, x3
  k_gemmF<1, 0, 1, 4, 4, 2, 2, 1, 0><<<dim3(512), dim3(256), 0, stream>>>(
      qp_hi, qp_lo, kvs, (const u16*)nullptr,
      sc, (u16*)nullptr, (u16*)nullptr, mask,
      1024, 512, 4, 4, (u64)524288, 7, (u64)524288, (u64)262144);
  // 4) softmax(sc) -> attn bf16
  k_softmax<<<dim3(4096), dim3(256), 0, stream>>>(sc, attn);
  // 5) out[z][t][r] = attn[z][t][s]*kvt[z][r][s]; bf16 x1; 256x128, 512 blocks
  k_gemmF<0, 0, 0, 8, 4, 2, 2, 0, 0><<<dim3(512), dim3(256), 0, stream>>>(
      attn, (const u16*)nullptr, kvt_hi, (const u16*)nullptr,
      out, (u16*)nullptr, (u16*)nullptr, (const float*)nullptr,
      512, 1024, 2, 8, (u64)262144, 31, (u64)524288, (u64)524288);

  (void)in_sizes; (void)n_in; (void)out_size; (void)ws_size;
}